// Round 1
// baseline (532.356 us; speedup 1.0000x reference)
//
#include <hip/hip_runtime.h>
#include <math.h>

// ---------------- types ----------------
typedef float  f32x4  __attribute__((ext_vector_type(4)));
typedef short  bf16x8 __attribute__((ext_vector_type(8)));

#define NTOK 8192
#define H    1024
#define FF   4096
#define NEXP 8
#define MAXTILES 72   // sum ceil(c_e/128) <= 8192/128 + 8

// fp32 -> bf16 RNE
__device__ __forceinline__ unsigned short f2bf(float f) {
    unsigned int u = __float_as_uint(f);
    u += 0x7fffu + ((u >> 16) & 1u);
    return (unsigned short)(u >> 16);
}

// async global->LDS, 16B per lane; LDS dest = wave-uniform base + lane*16
__device__ __forceinline__ void gload16(const void* g, void* l) {
    __builtin_amdgcn_global_load_lds((const __attribute__((address_space(1))) void*)g,
                                     (__attribute__((address_space(3))) void*)l, 16, 0, 0);
}

// ---------------- router: 1 wave per token ----------------
__global__ void __launch_bounds__(256)
router_k(const float* __restrict__ x, const float* __restrict__ rw, const float* __restrict__ rb,
         float* __restrict__ maxp, int* __restrict__ maxi, int* __restrict__ counts) {
    const int lane = threadIdx.x & 63;
    const int t = blockIdx.x * 4 + (threadIdx.x >> 6);
    const float4* xr = (const float4*)(x + (size_t)t * H);
    float acc[NEXP];
#pragma unroll
    for (int e = 0; e < NEXP; ++e) acc[e] = 0.f;
#pragma unroll
    for (int c = 0; c < 4; ++c) {
        float4 xv = xr[lane + 64 * c];
#pragma unroll
        for (int e = 0; e < NEXP; ++e) {
            float4 wv = ((const float4*)(rw + e * H))[lane + 64 * c];
            acc[e] += xv.x * wv.x + xv.y * wv.y + xv.z * wv.z + xv.w * wv.w;
        }
    }
#pragma unroll
    for (int e = 0; e < NEXP; ++e) {
#pragma unroll
        for (int off = 32; off > 0; off >>= 1) acc[e] += __shfl_xor(acc[e], off);
    }
    if (lane == 0) {
        float best = -1e30f; int bi = 0;
#pragma unroll
        for (int e = 0; e < NEXP; ++e) {
            float v = acc[e] + rb[e];
            acc[e] = v;
            if (v > best) { best = v; bi = e; }   // first-max tie-break like jnp.argmax
        }
        float s = 0.f;
#pragma unroll
        for (int e = 0; e < NEXP; ++e) s += __expf(acc[e] - best);
        maxp[t] = 1.0f / s;                       // max of softmax
        maxi[t] = bi;
        atomicAdd(&counts[bi], 1);
    }
}

// ---------------- scan: bucket offsets (128-aligned) + tile table ----------------
__global__ void scan_k(const int* __restrict__ counts, int* __restrict__ offs,
                       int* __restrict__ tile_e, int* __restrict__ tile_r0, int* __restrict__ ntiles) {
    int off = 0, ti = 0;
    for (int e = 0; e < NEXP; ++e) {
        offs[e] = off;
        int nt = (counts[e] + 127) >> 7;
        for (int j = 0; j < nt; ++j) { tile_e[ti] = e; tile_r0[ti] = off + (j << 7); ++ti; }
        off += nt << 7;
    }
    offs[NEXP] = off;
    *ntiles = ti;
}

// ---------------- gather tokens into bucketed bf16 A ----------------
__global__ void __launch_bounds__(256)
gather_k(const float* __restrict__ x, const int* __restrict__ maxi, const int* __restrict__ offs,
         int* __restrict__ cursor, int* __restrict__ perm, unsigned short* __restrict__ ab) {
    const int lane = threadIdx.x & 63;
    const int t = blockIdx.x * 4 + (threadIdx.x >> 6);
    int pos = 0;
    if (lane == 0) {
        int e = maxi[t];
        pos = offs[e] + atomicAdd(&cursor[e], 1);
        perm[pos] = t;
    }
    pos = __shfl(pos, 0);
    const float4* xr = (const float4*)(x + (size_t)t * H);
    ushort4* ar = (ushort4*)(ab + (size_t)pos * H);
#pragma unroll
    for (int c = 0; c < 4; ++c) {
        float4 v = xr[lane + 64 * c];
        ar[lane + 64 * c] = make_ushort4(f2bf(v.x), f2bf(v.y), f2bf(v.z), f2bf(v.w));
    }
}

// ---------------- fp32 -> bf16 weight convert ----------------
__global__ void __launch_bounds__(256)
cvt_k(const float4* __restrict__ src, ushort4* __restrict__ dst, int n4) {
    const int stride = gridDim.x * blockDim.x;
    for (int i = blockIdx.x * blockDim.x + threadIdx.x; i < n4; i += stride) {
        float4 v = src[i];
        dst[i] = make_ushort4(f2bf(v.x), f2bf(v.y), f2bf(v.z), f2bf(v.w));
    }
}

// ---------------- GEMM core: C[128x128] += A[128xK] * B[128xK]^T (both bf16 row-major, stride KB bytes)
// m97 structure: global_load_lds(16B) staging, 2 barriers / K-step(64), 16x16x32 MFMA.
// LDS XOR-swizzle (G4/rule#21): linear LDS dest, inverse-swizzled GLOBAL source, swizzled ds_read.
template<int KB>   // row stride in bytes (= 2*K)
__device__ __forceinline__ void gemm_core(const char* Ag, const char* Bg,
                                          unsigned short* As, unsigned short* Bs,
                                          f32x4 (&acc)[4][4]) {
    const int tid  = threadIdx.x;
    const int lane = tid & 63;
    const int wv   = tid >> 6;          // 4 waves, 2x2 over tile; each wave 64x64
    const int wr   = wv >> 1, wc = wv & 1;

    int goff[4];
#pragma unroll
    for (int c = 0; c < 4; ++c) {
        int op = c * 4096 + wv * 1024 + lane * 16;          // physical LDS byte this lane fills
        int ol = op ^ (((op >> 7) & 7) << 4);               // logical offset (swz is an involution)
        goff[c] = (ol >> 7) * KB + (ol & 127);              // row*stride + col bytes
    }
    const int rA  = (wr * 64 + (lane & 15)) * 128;
    const int rB  = (wc * 64 + (lane & 15)) * 128;
    const int xr  = (lane & 7) << 4;                        // (row&7)<<4 swizzle on read
    const int cb0 = (lane >> 4) << 4;

#pragma unroll 1
    for (int kt = 0; kt < KB / 128; ++kt) {
        const int kb = kt * 128;
#pragma unroll
        for (int c = 0; c < 4; ++c)
            gload16(Ag + goff[c] + kb, (char*)As + c * 4096 + wv * 1024);
#pragma unroll
        for (int c = 0; c < 4; ++c)
            gload16(Bg + goff[c] + kb, (char*)Bs + c * 4096 + wv * 1024);
        __syncthreads();                                    // drains vmcnt(0) for the LDS DMA
#pragma unroll
        for (int kk = 0; kk < 2; ++kk) {
            bf16x8 a[4], b[4];
            const int cb = kk * 64 + cb0;
#pragma unroll
            for (int m = 0; m < 4; ++m)
                a[m] = *(const bf16x8*)((const char*)As + ((rA + m * 2048 + cb) ^ xr));
#pragma unroll
            for (int n = 0; n < 4; ++n)
                b[n] = *(const bf16x8*)((const char*)Bs + ((rB + n * 2048 + cb) ^ xr));
#pragma unroll
            for (int m = 0; m < 4; ++m)
#pragma unroll
                for (int n = 0; n < 4; ++n)
                    asm volatile("v_mfma_f32_16x16x32_bf16 %0, %1, %2, %0"
                                 : "+v"(acc[m][n]) : "v"(a[m]), "v"(b[n]));
        }
        __syncthreads();
    }
}

// ---------------- GEMM1: inter = gelu(A @ w1[e]^T + b1[e]) ----------------
__global__ void __launch_bounds__(256)
gemm1_k(const unsigned short* __restrict__ ab, const unsigned short* __restrict__ w1b,
        const float* __restrict__ b1, unsigned short* __restrict__ inter,
        const int* __restrict__ tile_e, const int* __restrict__ tile_r0,
        const int* __restrict__ ntiles) {
    if (blockIdx.y >= (unsigned)*ntiles) return;
    __shared__ alignas(16) unsigned short As[128 * 64];
    __shared__ alignas(16) unsigned short Bs[128 * 64];
    const int e    = tile_e[blockIdx.y];
    const int row0 = tile_r0[blockIdx.y];
    const int f0   = blockIdx.x * 128;
    f32x4 acc[4][4];
#pragma unroll
    for (int m = 0; m < 4; ++m)
#pragma unroll
        for (int n = 0; n < 4; ++n)
#pragma unroll
            for (int j = 0; j < 4; ++j) acc[m][n][j] = 0.f;

    gemm_core<2 * H>((const char*)(ab + (size_t)row0 * H),
                     (const char*)(w1b + ((size_t)e * FF + f0) * H), As, Bs, acc);

    const int lane = threadIdx.x & 63;
    const int wv = threadIdx.x >> 6, wr = wv >> 1, wc = wv & 1;
    const int lr = (lane >> 4) << 2, lc = lane & 15;        // C/D: col=lane&15, row=(lane>>4)*4+reg
#pragma unroll
    for (int n = 0; n < 4; ++n) {
        const int gcol = f0 + wc * 64 + n * 16 + lc;
        const float bias = b1[e * FF + gcol];
#pragma unroll
        for (int m = 0; m < 4; ++m) {
            const int gr0 = row0 + wr * 64 + m * 16 + lr;
#pragma unroll
            for (int r = 0; r < 4; ++r) {
                float v = acc[m][n][r] + bias;
                float u = 0.5f * v * (1.0f + tanhf(0.7978845608028654f * v * (1.0f + 0.044715f * v * v)));
                inter[(size_t)(gr0 + r) * FF + gcol] = f2bf(u);
            }
        }
    }
}

// ---------------- GEMM2: out[token] = (inter @ w2[e]^T) * max_prob, scattered ----------------
__global__ void __launch_bounds__(256)
gemm2_k(const unsigned short* __restrict__ inter, const unsigned short* __restrict__ w2b,
        float* __restrict__ out,
        const int* __restrict__ tile_e, const int* __restrict__ tile_r0, const int* __restrict__ ntiles,
        const int* __restrict__ counts, const int* __restrict__ offs,
        const int* __restrict__ perm, const float* __restrict__ maxp) {
    if (blockIdx.y >= (unsigned)*ntiles) return;
    __shared__ alignas(16) unsigned short As[128 * 64];
    __shared__ alignas(16) unsigned short Bs[128 * 64];
    const int e    = tile_e[blockIdx.y];
    const int row0 = tile_r0[blockIdx.y];
    const int h0   = blockIdx.x * 128;
    f32x4 acc[4][4];
#pragma unroll
    for (int m = 0; m < 4; ++m)
#pragma unroll
        for (int n = 0; n < 4; ++n)
#pragma unroll
            for (int j = 0; j < 4; ++j) acc[m][n][j] = 0.f;

    gemm_core<2 * FF>((const char*)(inter + (size_t)row0 * FF),
                      (const char*)(w2b + ((size_t)e * H + h0) * FF), As, Bs, acc);

    const int lane = threadIdx.x & 63;
    const int wv = threadIdx.x >> 6, wr = wv >> 1, wc = wv & 1;
    const int lr = (lane >> 4) << 2, lc = lane & 15;
    const int cnt = counts[e], offe = offs[e];
#pragma unroll
    for (int m = 0; m < 4; ++m) {
#pragma unroll
        for (int r = 0; r < 4; ++r) {
            const int grow = row0 + wr * 64 + m * 16 + lr + r;
            if (grow - offe < cnt) {                         // skip padding rows
                const int t = perm[grow];
                const float p = maxp[t];
#pragma unroll
                for (int n = 0; n < 4; ++n)
                    out[(size_t)t * H + h0 + wc * 64 + n * 16 + lc] = acc[m][n][r] * p;
            }
        }
    }
}

// ---------------- out_bias = b2[e] * max_prob ----------------
__global__ void __launch_bounds__(256)
bias_k(const float* __restrict__ b2, const int* __restrict__ maxi, const float* __restrict__ maxp,
       float* __restrict__ outb) {
    const int t = blockIdx.x;
    const int c = threadIdx.x;
    const int e = maxi[t];
    const float p = maxp[t];
    float4 v = ((const float4*)(b2 + e * H))[c];
    float4 r; r.x = v.x * p; r.y = v.y * p; r.z = v.z * p; r.w = v.w * p;
    ((float4*)(outb + (size_t)t * H))[c] = r;
}

// ---------------- host launch ----------------
extern "C" void kernel_launch(void* const* d_in, const int* in_sizes, int n_in,
                              void* d_out, int out_size, void* d_ws, size_t ws_size,
                              hipStream_t stream) {
    const float* x  = (const float*)d_in[0];
    const float* rw = (const float*)d_in[1];
    const float* rb = (const float*)d_in[2];
    const float* w1 = (const float*)d_in[3];
    const float* b1 = (const float*)d_in[4];
    const float* w2 = (const float*)d_in[5];
    const float* b2 = (const float*)d_in[6];
    float* out  = (float*)d_out;                    // [8192][1024]
    float* outb = out + (size_t)NTOK * H;           // second tuple element

    // workspace layout (~219 MB)
    char* ws = (char*)d_ws;
    unsigned short* W1B   = (unsigned short*)(ws);                 //  67108864 B
    unsigned short* W2B   = (unsigned short*)(ws + 67108864);      //  67108864 B
    unsigned short* AB    = (unsigned short*)(ws + 134217728);     //  18874368 B (9216 x 1024 bf16)
    unsigned short* INTER = (unsigned short*)(ws + 153092096);     //  75497472 B (9216 x 4096 bf16)
    float* MAXP   = (float*)(ws + 228589568);                      //  32768 B
    int*   MAXI   = (int*)  (ws + 228622336);                      //  32768 B
    int*   PERM   = (int*)  (ws + 228655104);                      //  36864 B
    int*   COUNTS = (int*)  (ws + 228691968);
    int*   CURSOR = (int*)  (ws + 228692032);
    int*   OFFS   = (int*)  (ws + 228692096);
    int*   TILE_E = (int*)  (ws + 228692160);
    int*   TILE_R0= (int*)  (ws + 228692544);
    int*   NTILES = (int*)  (ws + 228692928);

    (void)hipMemsetAsync(COUNTS, 0, 128, stream);  // counts + cursor

    router_k<<<NTOK / 4, 256, 0, stream>>>(x, rw, rb, MAXP, MAXI, COUNTS);
    scan_k<<<1, 1, 0, stream>>>(COUNTS, OFFS, TILE_E, TILE_R0, NTILES);
    gather_k<<<NTOK / 4, 256, 0, stream>>>(x, MAXI, OFFS, CURSOR, PERM, AB);
    cvt_k<<<4096, 256, 0, stream>>>((const float4*)w1, (ushort4*)W1B, NEXP * FF * H / 4);
    cvt_k<<<4096, 256, 0, stream>>>((const float4*)w2, (ushort4*)W2B, NEXP * FF * H / 4);
    gemm1_k<<<dim3(FF / 128, MAXTILES), 256, 0, stream>>>(AB, W1B, b1, INTER, TILE_E, TILE_R0, NTILES);
    gemm2_k<<<dim3(H / 128, MAXTILES), 256, 0, stream>>>(INTER, W2B, out, TILE_E, TILE_R0, NTILES,
                                                         COUNTS, OFFS, PERM, MAXP);
    bias_k<<<NTOK, 256, 0, stream>>>(b2, MAXI, MAXP, outb);
}

// Round 2
// 400.605 us; speedup vs baseline: 1.3289x; 1.3289x over previous
//
#include <hip/hip_runtime.h>
#include <math.h>

typedef float  f32x4  __attribute__((ext_vector_type(4)));
typedef short  bf16x8 __attribute__((ext_vector_type(8)));

#define NTOK 8192
#define H    1024
#define FF   4096
#define NEXP 8
#define MAXTILES 40   // sum ceil(c_e/256) <= 8192/256 + 8

// fp32 -> bf16 RNE
__device__ __forceinline__ unsigned short f2bf(float f) {
    unsigned int u = __float_as_uint(f);
    u += 0x7fffu + ((u >> 16) & 1u);
    return (unsigned short)(u >> 16);
}

// async global->LDS, 16B/lane; LDS dest is wave-uniform base + lane*16
__device__ __forceinline__ void gload16(const void* g, void* l) {
    __builtin_amdgcn_global_load_lds((const __attribute__((address_space(1))) void*)g,
                                     (__attribute__((address_space(3))) void*)l, 16, 0, 0);
}

// ---------------- router: 1 wave per token ----------------
__global__ void __launch_bounds__(256)
router_k(const float* __restrict__ x, const float* __restrict__ rw, const float* __restrict__ rb,
         float* __restrict__ maxp, int* __restrict__ maxi, int* __restrict__ counts) {
    const int lane = threadIdx.x & 63;
    const int t = blockIdx.x * 4 + (threadIdx.x >> 6);
    const float4* xr = (const float4*)(x + (size_t)t * H);
    float acc[NEXP];
#pragma unroll
    for (int e = 0; e < NEXP; ++e) acc[e] = 0.f;
#pragma unroll
    for (int c = 0; c < 4; ++c) {
        float4 xv = xr[lane + 64 * c];
#pragma unroll
        for (int e = 0; e < NEXP; ++e) {
            float4 wv = ((const float4*)(rw + e * H))[lane + 64 * c];
            acc[e] += xv.x * wv.x + xv.y * wv.y + xv.z * wv.z + xv.w * wv.w;
        }
    }
#pragma unroll
    for (int e = 0; e < NEXP; ++e) {
#pragma unroll
        for (int off = 32; off > 0; off >>= 1) acc[e] += __shfl_xor(acc[e], off);
    }
    if (lane == 0) {
        float best = -1e30f; int bi = 0;
#pragma unroll
        for (int e = 0; e < NEXP; ++e) {
            float v = acc[e] + rb[e];
            acc[e] = v;
            if (v > best) { best = v; bi = e; }
        }
        float s = 0.f;
#pragma unroll
        for (int e = 0; e < NEXP; ++e) s += __expf(acc[e] - best);
        maxp[t] = 1.0f / s;
        maxi[t] = bi;
        atomicAdd(&counts[bi * 32], 1);   // 128B-padded: 8 independent L2 lines
    }
}

// ---------------- scan: 128-aligned buckets, 256-row tile table ----------------
__global__ void scan_k(const int* __restrict__ counts, int* __restrict__ offs,
                       int* __restrict__ tile_e, int* __restrict__ tile_r0, int* __restrict__ ntiles) {
    int off = 0, ti = 0;
    for (int e = 0; e < NEXP; ++e) {
        offs[e] = off;
        int c = counts[e * 32];
        int nt = (c + 255) >> 8;                       // 256-row GEMM tiles
        for (int j = 0; j < nt; ++j) { tile_e[ti] = e; tile_r0[ti] = off + (j << 8); ++ti; }
        off += ((c + 127) >> 7) << 7;                  // bucket advances 128-aligned
    }
    offs[NEXP] = off;
    *ntiles = ti;
}

// ---------------- gather tokens into bucketed bf16 A ----------------
__global__ void __launch_bounds__(256)
gather_k(const float* __restrict__ x, const int* __restrict__ maxi, const int* __restrict__ offs,
         int* __restrict__ cursor, int* __restrict__ perm, unsigned short* __restrict__ ab) {
    const int lane = threadIdx.x & 63;
    const int t = blockIdx.x * 4 + (threadIdx.x >> 6);
    int pos = 0;
    if (lane == 0) {
        int e = maxi[t];
        pos = offs[e] + atomicAdd(&cursor[e * 32], 1);  // padded cursors
        perm[pos] = t;
    }
    pos = __shfl(pos, 0);
    const float4* xr = (const float4*)(x + (size_t)t * H);
    ushort4* ar = (ushort4*)(ab + (size_t)pos * H);
#pragma unroll
    for (int c = 0; c < 4; ++c) {
        float4 v = xr[lane + 64 * c];
        ar[lane + 64 * c] = make_ushort4(f2bf(v.x), f2bf(v.y), f2bf(v.z), f2bf(v.w));
    }
}

// ---------------- fp32 -> bf16 convert, w1+w2 in one pass ----------------
__global__ void __launch_bounds__(256)
cvt_k(const float4* __restrict__ w1, const float4* __restrict__ w2,
      ushort4* __restrict__ d1, ushort4* __restrict__ d2, int n4) {
    const int stride = gridDim.x * blockDim.x;
    for (int i = blockIdx.x * blockDim.x + threadIdx.x; i < n4; i += stride) {
        float4 v = w1[i]; d1[i] = make_ushort4(f2bf(v.x), f2bf(v.y), f2bf(v.z), f2bf(v.w));
        float4 u = w2[i]; d2[i] = make_ushort4(f2bf(u.x), f2bf(u.y), f2bf(u.z), f2bf(u.w));
    }
}

// ================= 256x256 8-phase GEMM core (m201 template, derived schedule) =================
// C[256x256] += A[256xK] * B[256xK]^T, both bf16 row-major stride K.
// 8 waves (2M x 4N), per-wave 128x64. LDS: 2 buffers x (A 32KB + B 32KB) = 128KB,
// st_16x32 subtiled layout: subtile (16r x 32c) contiguous 1KB; within it
// col ^= 16 when (row&8) -> 4-way max bank aliasing on ds_read_b128.
// Staging: global_load_lds writes one whole subtile per wave-call; swizzle is
// pre-applied to the per-lane GLOBAL source address (rule #21: linear LDS dest).
// Half-slots: A-X = rows(bit6==0), A-Y = rows(bit6==1); B-0 = rows(bit5==0), B-1 = rest.
// Phase order per K-tile: (mh0,nh0)->(mh0,nh1)->(mh1,nh1)->(mh1,nh0); A-frags reused
// 2 phases, B-frags reused across the K-tile => 24 ds_read_b128 per K-tile per wave.
// Stage at phase p targets the slot retired at phase p-1; vmcnt(4) at ph4/ph8 covers
// every staged->consumed edge (3-4 half-tiles in flight, never drained to 0).

#define READ_A(BA, MH)                                                          \
  _Pragma("unroll") for (int j = 0; j < 4; ++j)                                 \
    _Pragma("unroll") for (int kk = 0; kk < 2; ++kk)                            \
      a_[j][kk] = *(const bf16x8*)((BA) + (wr*8 + (MH)*4 + j)*2048 + kk*1024 + aoffb);

#define READ_B(BB, NH, BR)                                                      \
  _Pragma("unroll") for (int j2 = 0; j2 < 2; ++j2)                              \
    _Pragma("unroll") for (int kk = 0; kk < 2; ++kk)                            \
      BR[j2][kk] = *(const bf16x8*)((BB) + (wc*4 + (NH)*2 + j2)*2048 + kk*1024 + aoffb);

#define MFMA_Q(MH, NH, BR)                                                      \
  __builtin_amdgcn_s_setprio(1);                                                \
  _Pragma("unroll") for (int kk = 0; kk < 2; ++kk)                              \
    _Pragma("unroll") for (int j = 0; j < 4; ++j)                               \
      _Pragma("unroll") for (int j2 = 0; j2 < 2; ++j2)                          \
        asm volatile("v_mfma_f32_16x16x32_bf16 %0, %1, %2, %0"                  \
          : "+v"(acc[(MH)*4 + j][(NH)*2 + j2]) : "v"(a_[j][kk]), "v"(BR[j2][kk])); \
  __builtin_amdgcn_s_setprio(0);

#define BAR() __builtin_amdgcn_s_barrier()

template<int KE>   // K in elements
__device__ __forceinline__ void gemm8_core(const char* __restrict__ Ag, const char* __restrict__ Bg,
                                           char* lds, f32x4 (&acc)[8][4]) {
    constexpr int LD2 = KE * 2;           // row stride bytes
    const int tid = threadIdx.x, l = tid & 63, w = tid >> 6;
    const int wr = w >> 2, wc = w & 3;
    const int term  = ((l >> 4) * 8) ^ (((l >> 3) & 1) << 4);
    const int aoffb = (l & 15) * 64 + term * 2;

    char* const A0 = lds;          char* const B0 = lds + 32768;
    char* const A1 = lds + 65536;  char* const B1 = lds + 98304;

    // stage precompute: q in {0,1} (2 gloads/half-tile/wave), half in {0,1}
    int offA[2][2], offB[2][2], dstA[2][2], dstB[2][2];
#pragma unroll
    for (int q = 0; q < 2; ++q) {
        const int s  = q * 8 + w;
        const int lr = l >> 2;
        const int h  = ((s >> 1) << 4) + lr;
        const int c  = ((s & 1) << 5) + (((l & 3) * 8) ^ ((l & 32) >> 1)); // inverse-swizzled col
#pragma unroll
        for (int half = 0; half < 2; ++half) {
            const int rA = (h & 63) + ((h >> 6) << 7) + (half << 6);
            const int rB = (h & 31) + ((h >> 5) << 6) + (half << 5);
            offA[q][half] = rA * LD2 + c * 2;
            offB[q][half] = rB * LD2 + c * 2;
            dstA[q][half] = ((((s >> 1) & 3) + (half << 2) + ((s >> 3) << 3)) << 11) + ((s & 1) << 10);
            dstB[q][half] = ((((s >> 1) & 1) + (half << 1) + ((s >> 2) << 2)) << 11) + ((s & 1) << 10);
        }
    }
    auto SA = [&](char* dst, int half, int kt) {
        gload16(Ag + offA[0][half] + kt * 128, dst + dstA[0][half]);
        gload16(Ag + offA[1][half] + kt * 128, dst + dstA[1][half]);
    };
    auto SB = [&](char* dst, int half, int kt) {
        gload16(Bg + offB[0][half] + kt * 128, dst + dstB[0][half]);
        gload16(Bg + offB[1][half] + kt * 128, dst + dstB[1][half]);
    };

    // prologue: kt0 complete + kt1 {A-X, B-0, B-1}; first 4 must land -> vmcnt(6)
    SA(A0, 0, 0); SB(B0, 0, 0); SB(B0, 1, 0); SA(A0, 1, 0);
    SA(A1, 0, 1); SB(B1, 0, 1); SB(B1, 1, 1);
    asm volatile("s_waitcnt vmcnt(6)" ::: "memory");
    BAR();

    constexpr int NKT = KE / 64;
    bf16x8 a_[4][2], b0_[2][2], b1_[2][2];
#pragma unroll 1
    for (int k0 = 0; k0 < NKT; k0 += 2) {
        const int k1 = k0 + 1;
        // ph1 (0,0) buf0
        READ_A(A0, 0) READ_B(B0, 0, b0_)
        SA(A1, 1, k1);
        BAR(); MFMA_Q(0, 0, b0_) BAR();
        // ph2 (0,1)
        READ_B(B0, 1, b1_)
        SA(A0, 0, k0 + 2);
        BAR(); MFMA_Q(0, 1, b1_) BAR();
        // ph3 (1,1)
        READ_A(A0, 1)
        SB(B0, 0, k0 + 2);
        BAR(); MFMA_Q(1, 1, b1_) BAR();
        // ph4 (1,0): no reads (regs reused)
        SB(B0, 1, k0 + 2);
        asm volatile("s_waitcnt vmcnt(4)" ::: "memory");
        BAR(); MFMA_Q(1, 0, b0_) BAR();
        // ph5 (0,0) buf1
        READ_A(A1, 0) READ_B(B1, 0, b0_)
        SA(A0, 1, k0 + 2);
        BAR(); MFMA_Q(0, 0, b0_) BAR();
        // ph6 (0,1)
        READ_B(B1, 1, b1_)
        SA(A1, 0, k1 + 2);
        BAR(); MFMA_Q(0, 1, b1_) BAR();
        // ph7 (1,1)
        READ_A(A1, 1)
        SB(B1, 0, k1 + 2);
        BAR(); MFMA_Q(1, 1, b1_) BAR();
        // ph8 (1,0)
        SB(B1, 1, k1 + 2);
        asm volatile("s_waitcnt vmcnt(4)" ::: "memory");
        BAR(); MFMA_Q(1, 0, b0_) BAR();
        // NOTE: stages for kt >= NKT read <=400B past the logical matrix; the ws
        // layout guarantees those bytes are allocated; the data is never consumed.
    }
}

// ---------------- GEMM1: inter = gelu(A @ w1[e]^T + b1[e]) ----------------
__global__ void __launch_bounds__(512, 2)
gemm1_k(const unsigned short* __restrict__ ab, const unsigned short* __restrict__ w1b,
        const float* __restrict__ b1, unsigned short* __restrict__ inter,
        const int* __restrict__ tile_e, const int* __restrict__ tile_r0,
        const int* __restrict__ ntiles, const int* __restrict__ offs) {
    if ((int)blockIdx.y >= *ntiles) return;
    __shared__ char lds[131072];
    const int e = tile_e[blockIdx.y], row0 = tile_r0[blockIdx.y];
    const int f0 = blockIdx.x * 256;
    f32x4 acc[8][4];
#pragma unroll
    for (int m = 0; m < 8; ++m)
#pragma unroll
        for (int n = 0; n < 4; ++n)
#pragma unroll
            for (int j = 0; j < 4; ++j) acc[m][n][j] = 0.f;

    gemm8_core<H>((const char*)(ab + (size_t)row0 * H),
                  (const char*)(w1b + ((size_t)e * FF + f0) * H), lds, acc);

    const int l = threadIdx.x & 63, w = threadIdx.x >> 6, wr = w >> 2, wc = w & 3;
    const int rend = offs[e + 1];        // mask rows straddling into next bucket
#pragma unroll
    for (int n = 0; n < 4; ++n) {
        const int col = f0 + wc * 64 + n * 16 + (l & 15);
        const float bias = b1[e * FF + col];
#pragma unroll
        for (int m = 0; m < 8; ++m) {
            const int r0 = row0 + wr * 128 + m * 16 + ((l >> 4) << 2);
#pragma unroll
            for (int j = 0; j < 4; ++j) {
                if (r0 + j < rend) {
                    float v = acc[m][n][j] + bias;
                    // 0.5v(1+tanh(z)) = v - v/(e^{2z}+1),  z = 0.79788456*v*(1+0.044715 v^2)
                    float ex = __expf(1.5957691216057308f * v * (1.0f + 0.044715f * v * v));
                    float u  = v - v / (ex + 1.0f);
                    inter[(size_t)(r0 + j) * FF + col] = f2bf(u);
                }
            }
        }
    }
}

// ---------------- GEMM2: out = (inter @ w2[e]^T)*p scattered; outb = b2[e]*p fused ----------------
__global__ void __launch_bounds__(512, 2)
gemm2_k(const unsigned short* __restrict__ inter, const unsigned short* __restrict__ w2b,
        const float* __restrict__ b2, float* __restrict__ out, float* __restrict__ outb,
        const int* __restrict__ tile_e, const int* __restrict__ tile_r0, const int* __restrict__ ntiles,
        const int* __restrict__ counts, const int* __restrict__ offs,
        const int* __restrict__ perm, const float* __restrict__ maxp) {
    if ((int)blockIdx.y >= *ntiles) return;
    __shared__ char lds[131072];
    const int e = tile_e[blockIdx.y], row0 = tile_r0[blockIdx.y];
    const int h0 = blockIdx.x * 256;
    f32x4 acc[8][4];
#pragma unroll
    for (int m = 0; m < 8; ++m)
#pragma unroll
        for (int n = 0; n < 4; ++n)
#pragma unroll
            for (int j = 0; j < 4; ++j) acc[m][n][j] = 0.f;

    gemm8_core<FF>((const char*)(inter + (size_t)row0 * FF),
                   (const char*)(w2b + ((size_t)e * H + h0) * FF), lds, acc);

    const int l = threadIdx.x & 63, w = threadIdx.x >> 6, wr = w >> 2, wc = w & 3;
    const int cnt = counts[e * 32], offe = offs[e];
#pragma unroll
    for (int m = 0; m < 8; ++m) {
#pragma unroll
        for (int j = 0; j < 4; ++j) {
            const int grow = row0 + wr * 128 + m * 16 + ((l >> 4) << 2) + j;
            if (grow - offe < cnt) {
                const int t = perm[grow];
                const float p = maxp[t];
#pragma unroll
                for (int n = 0; n < 4; ++n) {
                    const int col = h0 + wc * 64 + n * 16 + (l & 15);
                    out [(size_t)t * H + col] = acc[m][n][j] * p;
                    outb[(size_t)t * H + col] = b2[e * H + col] * p;
                }
            }
        }
    }
}

// ---------------- host launch ----------------
extern "C" void kernel_launch(void* const* d_in, const int* in_sizes, int n_in,
                              void* d_out, int out_size, void* d_ws, size_t ws_size,
                              hipStream_t stream) {
    const float* x  = (const float*)d_in[0];
    const float* rw = (const float*)d_in[1];
    const float* rb = (const float*)d_in[2];
    const float* w1 = (const float*)d_in[3];
    const float* b1 = (const float*)d_in[4];
    const float* w2 = (const float*)d_in[5];
    const float* b2 = (const float*)d_in[6];
    float* out  = (float*)d_out;
    float* outb = out + (size_t)NTOK * H;

    // workspace (bigs first; same footprint as round 0 + ~2KB)
    char* ws = (char*)d_ws;
    unsigned short* W1B   = (unsigned short*)(ws);                 // 67108864
    unsigned short* W2B   = (unsigned short*)(ws + 67108864);      // 67108864
    unsigned short* AB    = (unsigned short*)(ws + 134217728);     // 18874368 (9216 x 1024)
    unsigned short* INTER = (unsigned short*)(ws + 153092096);     // 75497472 (9216 x 4096)
    float* MAXP    = (float*)(ws + 228589568);                     // 32768
    int*   MAXI    = (int*)  (ws + 228622336);                     // 32768
    int*   PERM    = (int*)  (ws + 228655104);                     // 36864
    int*   COUNTS  = (int*)  (ws + 228691968);                     // 1024 (8 x 128B-padded)
    int*   CURSOR  = (int*)  (ws + 228692992);                     // 1024
    int*   OFFS    = (int*)  (ws + 228694016);                     // 64
    int*   TILE_E  = (int*)  (ws + 228694080);                     // 256
    int*   TILE_R0 = (int*)  (ws + 228694336);                     // 256
    int*   NTILES  = (int*)  (ws + 228694592);

    (void)hipMemsetAsync(COUNTS, 0, 2048, stream);   // counts + cursors

    router_k<<<NTOK / 4, 256, 0, stream>>>(x, rw, rb, MAXP, MAXI, COUNTS);
    scan_k<<<1, 1, 0, stream>>>(COUNTS, OFFS, TILE_E, TILE_R0, NTILES);
    gather_k<<<NTOK / 4, 256, 0, stream>>>(x, MAXI, OFFS, CURSOR, PERM, AB);
    cvt_k<<<4096, 256, 0, stream>>>((const float4*)w1, (const float4*)w2,
                                    (ushort4*)W1B, (ushort4*)W2B, NEXP * FF * H / 4);
    gemm1_k<<<dim3(FF / 256, MAXTILES), 512, 0, stream>>>(AB, W1B, b1, INTER,
                                                          TILE_E, TILE_R0, NTILES, OFFS);
    gemm2_k<<<dim3(H / 256, MAXTILES), 512, 0, stream>>>(INTER, W2B, b2, out, outb,
                                                         TILE_E, TILE_R0, NTILES,
                                                         COUNTS, OFFS, PERM, MAXP);
}